// Round 1
// baseline (750.609 us; speedup 1.0000x reference)
//
#include <hip/hip_runtime.h>
#include <cmath>

// FFTConv via diagonal complex SSM scan.
// y[b,h,l] = tanh( Re(sum_p BC[h,p] * s_p[b,h,l]) + D[h]*u[b,h,l] )
// s_p[l] = A_p * s_p[l-1] + u[l]  (circular; |A|<=0.99 so influence dies in ~1024 steps)
//
// Parallelization: L split into 4 chunks of 2048, each with a 1024-step warm-up
// scan (wrapped circularly) to establish the state — truncation error ~|A|^1024 <= 3.4e-5.
// One wave handles 8 sequences; each lane handles 8 poles of one sequence
// (lane = seq_id*8 + pole_group). Per-step 8-lane shfl_xor reduction gives y[l].

#define LSEQ 8192
#define HDIM 256
#define PDIM 64
#define CHUNK 2048
#define WARM 1024
#define TILE 128
#define WAVES_PER_BLOCK 4

__global__ __launch_bounds__(256, 2)
void fftconv_scan(const float* __restrict__ u, const float* __restrict__ A_re,
                  const float* __restrict__ A_im, const float* __restrict__ BC_re,
                  const float* __restrict__ BC_im, const float* __restrict__ Dv,
                  float* __restrict__ out) {
    // per-wave private tiles; row stride 132 breaks bank conflicts
    __shared__ float u_t[WAVES_PER_BLOCK][8][TILE + 4];
    __shared__ float y_t[WAVES_PER_BLOCK][8][TILE + 4];

    const int lane = threadIdx.x & 63;
    const int wv   = threadIdx.x >> 6;
    const int w    = blockIdx.x * WAVES_PER_BLOCK + wv;   // 0..2047
    const int chunk = w >> 9;                             // 0..3
    const int sb    = (w & 511) * 8;                      // sequence base (of 4096)
    const int seq_id = lane >> 3;                         // 0..7 within wave
    const int pg     = lane & 7;                          // pole group 0..7

    const int h = (sb + seq_id) & (HDIM - 1);

    float a_re[8], a_im[8], bc_re[8], bc_im[8], s_re[8], s_im[8];
#pragma unroll
    for (int j = 0; j < 8; ++j) {
        int p = pg * 8 + j;
        a_re[j] = A_re[p];
        a_im[j] = A_im[p];
        bc_re[j] = BC_re[h * PDIM + p];
        bc_im[j] = BC_im[h * PDIM + p];
        s_re[j] = 0.f;
        s_im[j] = 0.f;
    }
    const float dval = Dv[h];

    const int l0 = (chunk * CHUNK - WARM) & (LSEQ - 1);   // warm-up start (wraps)
    const int NT = (WARM + CHUNK) / TILE;                 // 24 tiles
    const int NWARM = WARM / TILE;                        // 8 warm tiles

    for (int t = 0; t < NT; ++t) {
        const int tb = (l0 + t * TILE) & (LSEQ - 1);      // tile base, 128-aligned, no wrap inside

        // stage u tile: 8 rows x 128 floats, coalesced float4
#pragma unroll
        for (int k = 0; k < 4; ++k) {
            int idx = k * 64 + lane;                      // 0..255
            int row = idx >> 5;                           // 0..7
            int c4  = idx & 31;                           // float4 column
            float4 v = *((const float4*)(u + (size_t)(sb + row) * LSEQ + tb) + c4);
            *((float4*)&u_t[wv][row][0] + c4) = v;
        }
        __syncthreads();

        const float* ur = &u_t[wv][seq_id][0];
        if (t < NWARM) {
            // warm-up: state update only (4 FMA / pole / step)
#pragma unroll 4
            for (int i = 0; i < TILE; ++i) {
                float uv = ur[i];
#pragma unroll
                for (int j = 0; j < 8; ++j) {
                    float nr = fmaf(a_re[j], s_re[j], uv);
                    nr = fmaf(-a_im[j], s_im[j], nr);
                    float ni = fmaf(a_re[j], s_im[j], a_im[j] * s_re[j]);
                    s_re[j] = nr;
                    s_im[j] = ni;
                }
            }
            __syncthreads();
        } else {
            // emit: state update + projection (6 FMA / pole / step)
            float* yr = &y_t[wv][seq_id][0];
#pragma unroll 4
            for (int i = 0; i < TILE; ++i) {
                float uv = ur[i];
                float acc = 0.f;
#pragma unroll
                for (int j = 0; j < 8; ++j) {
                    float nr = fmaf(a_re[j], s_re[j], uv);
                    nr = fmaf(-a_im[j], s_im[j], nr);
                    float ni = fmaf(a_re[j], s_im[j], a_im[j] * s_re[j]);
                    s_re[j] = nr;
                    s_im[j] = ni;
                    acc = fmaf(bc_re[j], nr, acc);
                    acc = fmaf(-bc_im[j], ni, acc);
                }
                // reduce over the 8 pole-group lanes (contiguous, xor 1/2/4)
                acc += __shfl_xor(acc, 1);
                acc += __shfl_xor(acc, 2);
                acc += __shfl_xor(acc, 4);
                if (pg == 0) yr[i] = fmaf(dval, uv, acc);
            }
            __syncthreads();

            // flush y tile: tanh + coalesced float4 stores
#pragma unroll
            for (int k = 0; k < 4; ++k) {
                int idx = k * 64 + lane;
                int row = idx >> 5;
                int c4  = idx & 31;
                float4 v = *((float4*)&y_t[wv][row][0] + c4);
                v.x = tanhf(v.x);
                v.y = tanhf(v.y);
                v.z = tanhf(v.z);
                v.w = tanhf(v.w);
                *((float4*)(out + (size_t)(sb + row) * LSEQ + tb) + c4) = v;
            }
        }
    }
}

extern "C" void kernel_launch(void* const* d_in, const int* in_sizes, int n_in,
                              void* d_out, int out_size, void* d_ws, size_t ws_size,
                              hipStream_t stream) {
    const float* u     = (const float*)d_in[0];
    const float* A_re  = (const float*)d_in[1];
    const float* A_im  = (const float*)d_in[2];
    const float* BC_re = (const float*)d_in[3];
    const float* BC_im = (const float*)d_in[4];
    const float* Dv    = (const float*)d_in[5];
    float* out = (float*)d_out;

    dim3 grid(512), block(256);
    hipLaunchKernelGGL(fftconv_scan, grid, block, 0, stream,
                       u, A_re, A_im, BC_re, BC_im, Dv, out);
}

// Round 2
// 667.562 us; speedup vs baseline: 1.1244x; 1.1244x over previous
//
#include <hip/hip_runtime.h>
#include <cmath>

// FFTConv via diagonal complex SSM scan (circular conv with sum-of-64-geometric kernels).
// y[s,l] = tanh( Re(sum_p BC[h,p] * state_p[l]) + D[h]*u[s,l] ),  state' = A*state + u.
// |A| <= 0.99 -> 1024-step warm-up scan makes chunks independent (err ~3.4e-5).
//
// R2 layout: block = 256 thr = 4 waves, handles 16 sequences x 1 chunk(2048).
//   wave wv owns poles [wv*16, wv*16+16); lane = seq*4 + pg; pg owns 4 poles.
//   In-quad reduction via DPP quad_perm (xor1,xor2) -- no ds_swizzle.
//   Per-wave partial y tiles in LDS, combined+tanh'd+stored in flush phase.
// Grid = 256 seq-groups * 4 chunks = 1024 blocks = 4096 waves = 16 waves/CU.

#define LSEQ 8192
#define HDIM 256
#define PDIM 64
#define CHUNK 2048
#define WARM 1024
#define TILE 64
#define NT ((WARM + CHUNK) / TILE)   // 48 tiles
#define NWARM (WARM / TILE)          // 16 warm tiles

__device__ __forceinline__ float quad_add_xor1(float x) {
    int v = __builtin_amdgcn_update_dpp(0, __float_as_int(x), 0xB1, 0xF, 0xF, true);
    return x + __int_as_float(v);
}
__device__ __forceinline__ float quad_add_xor2(float x) {
    int v = __builtin_amdgcn_update_dpp(0, __float_as_int(x), 0x4E, 0xF, 0xF, true);
    return x + __int_as_float(v);
}

__global__ __launch_bounds__(256, 4)
void fftconv_scan(const float* __restrict__ u, const float* __restrict__ A_re,
                  const float* __restrict__ A_im, const float* __restrict__ BC_re,
                  const float* __restrict__ BC_im, const float* __restrict__ Dv,
                  float* __restrict__ out) {
    __shared__ __align__(16) float u_t[16][TILE + 4];      // row stride 68 -> 2-way max (free)
    __shared__ float y_p[4][16][TILE + 1];                 // row stride 65 -> conflict-free writes

    const int tid  = threadIdx.x;
    const int lane = tid & 63;
    const int wv   = tid >> 6;            // wave: pole half-quarter [wv*16, wv*16+16)
    const int seq_id = lane >> 2;         // 0..15
    const int pg     = lane & 3;          // 0..3, owns 4 poles

    const int chunk = blockIdx.x >> 8;    // 0..3
    const int sb    = (blockIdx.x & 255) * 16;            // sequence base (of 4096)
    const int h     = (sb + seq_id) & (HDIM - 1);

    float a_re[4], a_im[4], bc_re[4], bc_im[4], s_re[4], s_im[4];
#pragma unroll
    for (int j = 0; j < 4; ++j) {
        int p = wv * 16 + pg * 4 + j;
        a_re[j] = A_re[p];
        a_im[j] = A_im[p];
        bc_re[j] = BC_re[h * PDIM + p];
        bc_im[j] = BC_im[h * PDIM + p];
        s_re[j] = 0.f;
        s_im[j] = 0.f;
    }
    const float dval = Dv[h];

    const int l0 = (chunk * CHUNK - WARM) & (LSEQ - 1);   // warm-up start (wraps, 64-aligned)

    // stage tile 0
    {
        const int tb = l0;
        int row = tid >> 4, c4 = tid & 15;
        float4 v = *((const float4*)(u + (size_t)(sb + row) * LSEQ + tb) + c4);
        *(float4*)&u_t[row][c4 * 4] = v;
    }

    for (int t = 0; t < NT; ++t) {
        __syncthreads();   // staging done / y_p free for rewrite

        if (t < NWARM) {
            // warm-up: state update only
#pragma unroll 2
            for (int i = 0; i < TILE; ++i) {
                float uv = u_t[seq_id][i];
#pragma unroll
                for (int j = 0; j < 4; ++j) {
                    float nr = fmaf(a_re[j], s_re[j], uv);
                    nr = fmaf(-a_im[j], s_im[j], nr);
                    float ni = fmaf(a_re[j], s_im[j], a_im[j] * s_re[j]);
                    s_re[j] = nr;
                    s_im[j] = ni;
                }
            }
        } else {
            // emit: state update + projection + in-quad DPP reduce
#pragma unroll 2
            for (int i = 0; i < TILE; ++i) {
                float uv = u_t[seq_id][i];
                float acc = 0.f;
#pragma unroll
                for (int j = 0; j < 4; ++j) {
                    float nr = fmaf(a_re[j], s_re[j], uv);
                    nr = fmaf(-a_im[j], s_im[j], nr);
                    float ni = fmaf(a_re[j], s_im[j], a_im[j] * s_re[j]);
                    s_re[j] = nr;
                    s_im[j] = ni;
                    acc = fmaf(bc_re[j], nr, acc);
                    acc = fmaf(-bc_im[j], ni, acc);
                }
                acc = quad_add_xor1(acc);
                acc = quad_add_xor2(acc);
                if (pg == 0)
                    y_p[wv][seq_id][i] = (wv == 0) ? fmaf(dval, uv, acc) : acc;
            }
        }

        __syncthreads();   // y_p ready; u_t consumed

        // flush (emit tiles) + stage next tile, concurrently
        if (t >= NWARM) {
            const int tb = (l0 + t * TILE) & (LSEQ - 1);
#pragma unroll
            for (int k = 0; k < 4; ++k) {
                int idx = k * 256 + tid;
                int sq = idx >> 6, i = idx & 63;
                float v = y_p[0][sq][i] + y_p[1][sq][i] + y_p[2][sq][i] + y_p[3][sq][i];
                out[(size_t)(sb + sq) * LSEQ + tb + i] = tanhf(v);
            }
        }
        if (t + 1 < NT) {
            const int tb = (l0 + (t + 1) * TILE) & (LSEQ - 1);
            int row = tid >> 4, c4 = tid & 15;
            float4 v = *((const float4*)(u + (size_t)(sb + row) * LSEQ + tb) + c4);
            *(float4*)&u_t[row][c4 * 4] = v;
        }
    }
}

extern "C" void kernel_launch(void* const* d_in, const int* in_sizes, int n_in,
                              void* d_out, int out_size, void* d_ws, size_t ws_size,
                              hipStream_t stream) {
    const float* u     = (const float*)d_in[0];
    const float* A_re  = (const float*)d_in[1];
    const float* A_im  = (const float*)d_in[2];
    const float* BC_re = (const float*)d_in[3];
    const float* BC_im = (const float*)d_in[4];
    const float* Dv    = (const float*)d_in[5];
    float* out = (float*)d_out;

    dim3 grid(1024), block(256);
    hipLaunchKernelGGL(fftconv_scan, grid, block, 0, stream,
                       u, A_re, A_im, BC_re, BC_im, Dv, out);
}

// Round 3
// 352.399 us; speedup vs baseline: 2.1300x; 1.8943x over previous
//
#include <hip/hip_runtime.h>
#include <cmath>

// FFTConv via chunked diagonal SSM + MFMA.
//
// y[n] = tanh( sum_{d>=0} k_d u[n-d] (circular) + D*u[n] ),  k_d = Re sum_p bc_p A_p^d.
// Chunk n = c*128 + r (nc=64 chunks):
//   y[c,r] = sum_j T'[r][j] u[c*128+j]  +  Re sum_p bc_p A_p^{r+1} sB_p[c]
//   T'[r][j] = k_{r-j} (j<=r) + D*(j==r)          (intra-chunk + D skip, one GEMM)
//   sB[c+1]  = A^128 sB[c] + S_in[c],  S_in[c] = sum_j A^{127-j} u[c*128+j]  (GEMM)
// Circular init: 8-chunk warm-up scan (|A|^1024 <= 3.4e-5 truncation).
//
// prep kernel: builds fp16 tables  A2[h] = [G_h | T'_h] (128x256),  W (128x128),
// A^128 (fp32) in ws.  main kernel: one block per (h,b) sequence: stage u->fp16,
// GEMM1 (MFMA 32x32x16_f16), 72-step scan on wave 0, GEMM2, tanh, store.
// Compute is ~26 GFLOP total -> HBM-bound (~285 MB).

typedef _Float16 half8 __attribute__((ext_vector_type(8)));
typedef _Float16 half4v __attribute__((ext_vector_type(4)));
typedef float floatx16 __attribute__((ext_vector_type(16)));

#define NC 64
#define CM 128
#define ROWP 136   // padded LDS row stride (halves): 272 B, 16B-aligned rows
#define A2_BYTES ((size_t)256 * 128 * 256 * 2)
#define W_BYTES  ((size_t)128 * 128 * 2)
#define AM_OFF   (A2_BYTES + W_BYTES)

__device__ __forceinline__ float fast_tanh(float x) {
    float e2 = __expf(2.0f * x);
    return 1.0f - 2.0f / (e2 + 1.0f);   // exact +/-1 at saturation, no NaN
}

__global__ void fftconv_prep(const float* __restrict__ A_re, const float* __restrict__ A_im,
                             const float* __restrict__ BC_re, const float* __restrict__ BC_im,
                             const float* __restrict__ Dv, char* __restrict__ ws) {
    __shared__ float rr[64], th[64], br[64], bi[64];
    __shared__ float kk[CM];
    const int h = blockIdx.x, tid = threadIdx.x;
    if (tid < 64) {
        float x = A_re[tid], y = A_im[tid];
        rr[tid] = log2f(sqrtf(x * x + y * y));   // log2|A|
        th[tid] = atan2f(y, x);                  // arg(A)
        br[tid] = BC_re[h * 64 + tid];
        bi[tid] = BC_im[h * 64 + tid];
    }
    __syncthreads();
    if (tid < CM) {   // kernel taps k_d, d = 0..127
        float d = (float)tid, s = 0.f;
        for (int p = 0; p < 64; ++p) {
            float mag = exp2f(d * rr[p]);
            float ang = d * th[p];
            s += mag * (br[p] * cosf(ang) - bi[p] * sinf(ang));
        }
        kk[tid] = s;
    }
    __syncthreads();
    _Float16* A2 = (_Float16*)ws + (size_t)h * 128 * 256;
    const float Dh = Dv[h];
    // G part: A2[r][pc] = pc<64 ? Re(bc_p A^{r+1}) : -Im(bc_p A^{r+1})
    for (int idx = tid; idx < 128 * 128; idx += 256) {
        int r = idx >> 7, pc = idx & 127, p = pc & 63;
        float e = (float)(r + 1);
        float mag = exp2f(e * rr[p]);
        float ang = e * th[p];
        float cr = mag * cosf(ang), ci = mag * sinf(ang);
        float val = (pc < 64) ? (br[p] * cr - bi[p] * ci) : -(br[p] * ci + bi[p] * cr);
        A2[r * 256 + pc] = (_Float16)val;
    }
    // T' part: A2[r][128+j] = k_{r-j} (j<=r) + D*(j==r)
    for (int idx = tid; idx < 128 * 128; idx += 256) {
        int r = idx >> 7, j = idx & 127;
        float v = (j <= r) ? kk[r - j] : 0.f;
        if (j == r) v += Dh;
        A2[r * 256 + CM + j] = (_Float16)v;
    }
    if (h == 0) {
        _Float16* W = (_Float16*)(ws + A2_BYTES);   // W[pc][j] = comp(A_p^{127-j})
        for (int idx = tid; idx < 128 * 128; idx += 256) {
            int pc = idx >> 7, j = idx & 127, p = pc & 63;
            float e = (float)(127 - j);
            float mag = exp2f(e * rr[p]);
            float ang = e * th[p];
            float v = (pc < 64) ? mag * cosf(ang) : mag * sinf(ang);
            W[pc * 128 + j] = (_Float16)v;
        }
        if (tid < 64) {   // A^128 fp32 for the scan
            float mag = exp2f(128.f * rr[tid]);
            float ang = 128.f * th[tid];
            float* aM = (float*)(ws + AM_OFF);
            aM[tid] = mag * cosf(ang);
            aM[64 + tid] = mag * sinf(ang);
        }
    }
}

__global__ __launch_bounds__(256, 2)
void fftconv_main(const float* __restrict__ u, const char* __restrict__ ws,
                  float* __restrict__ out) {
    __shared__ __align__(16) _Float16 u16p[NC * ROWP];  // u chunks [c][j], fp16
    __shared__ __align__(16) _Float16 S16[NC * ROWP];   // S_in then sB  [c][pc]

    const int tid = threadIdx.x;
    const int lane = tid & 63;
    const int wv = tid >> 6;
    const int h = blockIdx.x >> 4;
    const int bb = blockIdx.x & 15;
    const float* ub = u + ((size_t)bb * 256 + h) * 8192;
    float* yb = out + ((size_t)bb * 256 + h) * 8192;

    // stage u -> fp16 padded tiles (coalesced float4 reads)
#pragma unroll
    for (int i = 0; i < 8; ++i) {
        int e4 = i * 256 + tid;
        float4 v = ((const float4*)ub)[e4];
        int el = e4 << 2;
        int c = el >> 7, j = el & 127;
        half4v hv = { (_Float16)v.x, (_Float16)v.y, (_Float16)v.z, (_Float16)v.w };
        *(half4v*)&u16p[c * ROWP + j] = hv;
    }
    __syncthreads();

    const int mrow = (wv << 5) + (lane & 31);      // output row (pc / r)
    const int kh = (lane >> 5) << 3;               // k-offset within frag
    const int ncol = lane & 31;                    // output column (c)

    // ---- GEMM1: S_in = W * u_chunks ----
    {
        const _Float16* Wg = (const _Float16*)(ws + A2_BYTES);
        floatx16 acc0 = {}; floatx16 acc1 = {};
#pragma unroll
        for (int s = 0; s < 8; ++s) {
            int k0 = (s << 4) + kh;
            half8 af = *(const half8*)(Wg + mrow * CM + k0);
            half8 b0 = *(const half8*)&u16p[ncol * ROWP + k0];
            half8 b1 = *(const half8*)&u16p[(ncol + 32) * ROWP + k0];
            acc0 = __builtin_amdgcn_mfma_f32_32x32x16_f16(af, b0, acc0, 0, 0, 0);
            acc1 = __builtin_amdgcn_mfma_f32_32x32x16_f16(af, b1, acc1, 0, 0, 0);
        }
        const int pc0 = (wv << 5) + ((lane >> 5) << 2);
#pragma unroll
        for (int g = 0; g < 4; ++g) {
            half4v h0 = { (_Float16)acc0[4 * g + 0], (_Float16)acc0[4 * g + 1],
                          (_Float16)acc0[4 * g + 2], (_Float16)acc0[4 * g + 3] };
            *(half4v*)&S16[ncol * ROWP + pc0 + 8 * g] = h0;
            half4v h1 = { (_Float16)acc1[4 * g + 0], (_Float16)acc1[4 * g + 1],
                          (_Float16)acc1[4 * g + 2], (_Float16)acc1[4 * g + 3] };
            *(half4v*)&S16[(ncol + 32) * ROWP + pc0 + 8 * g] = h1;
        }
    }
    __syncthreads();

    // ---- serial chunk-state scan (wave 0, lane = pole), in-place S_in -> sB ----
    if (wv == 0) {
        const float* aM = (const float*)(ws + AM_OFF);
        const float amr = aM[lane], ami = aM[64 + lane];
        float sr = 0.f, si = 0.f;
#pragma unroll
        for (int c = NC - 8; c < NC; ++c) {   // circular warm-up
            float xr = (float)S16[c * ROWP + lane];
            float xi = (float)S16[c * ROWP + 64 + lane];
            float nr = fmaf(amr, sr, fmaf(-ami, si, xr));
            float ni = fmaf(amr, si, fmaf(ami, sr, xi));
            sr = nr; si = ni;
        }
#pragma unroll
        for (int c = 0; c < NC; ++c) {
            float xr = (float)S16[c * ROWP + lane];
            float xi = (float)S16[c * ROWP + 64 + lane];
            S16[c * ROWP + lane] = (_Float16)sr;        // store ENTERING state
            S16[c * ROWP + 64 + lane] = (_Float16)si;
            float nr = fmaf(amr, sr, fmaf(-ami, si, xr));
            float ni = fmaf(amr, si, fmaf(ami, sr, xi));
            sr = nr; si = ni;
        }
    }
    __syncthreads();

    // ---- GEMM2: y = [G|T'] * [sB; u_chunk], then tanh + store ----
    {
        const _Float16* Ag = (const _Float16*)ws + ((size_t)h * CM + mrow) * 256;
        floatx16 acc0 = {}; floatx16 acc1 = {};
#pragma unroll
        for (int s = 0; s < 8; ++s) {          // k = 0..127: G * sB
            int k0 = (s << 4) + kh;
            half8 af = *(const half8*)(Ag + k0);
            half8 b0 = *(const half8*)&S16[ncol * ROWP + k0];
            half8 b1 = *(const half8*)&S16[(ncol + 32) * ROWP + k0];
            acc0 = __builtin_amdgcn_mfma_f32_32x32x16_f16(af, b0, acc0, 0, 0, 0);
            acc1 = __builtin_amdgcn_mfma_f32_32x32x16_f16(af, b1, acc1, 0, 0, 0);
        }
#pragma unroll
        for (int s = 0; s < 8; ++s) {          // k = 128..255: T' * u
            int k0 = (s << 4) + kh;
            half8 af = *(const half8*)(Ag + CM + k0);
            half8 b0 = *(const half8*)&u16p[ncol * ROWP + k0];
            half8 b1 = *(const half8*)&u16p[(ncol + 32) * ROWP + k0];
            acc0 = __builtin_amdgcn_mfma_f32_32x32x16_f16(af, b0, acc0, 0, 0, 0);
            acc1 = __builtin_amdgcn_mfma_f32_32x32x16_f16(af, b1, acc1, 0, 0, 0);
        }
        const int r0 = (wv << 5) + ((lane >> 5) << 2);
#pragma unroll
        for (int g = 0; g < 4; ++g) {
            float4 o0;
            o0.x = fast_tanh(acc0[4 * g + 0]); o0.y = fast_tanh(acc0[4 * g + 1]);
            o0.z = fast_tanh(acc0[4 * g + 2]); o0.w = fast_tanh(acc0[4 * g + 3]);
            *(float4*)(yb + (size_t)ncol * CM + r0 + 8 * g) = o0;
            float4 o1;
            o1.x = fast_tanh(acc1[4 * g + 0]); o1.y = fast_tanh(acc1[4 * g + 1]);
            o1.z = fast_tanh(acc1[4 * g + 2]); o1.w = fast_tanh(acc1[4 * g + 3]);
            *(float4*)(yb + (size_t)(ncol + 32) * CM + r0 + 8 * g) = o1;
        }
    }
}

extern "C" void kernel_launch(void* const* d_in, const int* in_sizes, int n_in,
                              void* d_out, int out_size, void* d_ws, size_t ws_size,
                              hipStream_t stream) {
    const float* u     = (const float*)d_in[0];
    const float* A_re  = (const float*)d_in[1];
    const float* A_im  = (const float*)d_in[2];
    const float* BC_re = (const float*)d_in[3];
    const float* BC_im = (const float*)d_in[4];
    const float* Dv    = (const float*)d_in[5];
    float* out = (float*)d_out;
    char* ws = (char*)d_ws;

    hipLaunchKernelGGL(fftconv_prep, dim3(256), dim3(256), 0, stream,
                       A_re, A_im, BC_re, BC_im, Dv, ws);
    hipLaunchKernelGGL(fftconv_main, dim3(4096), dim3(256), 0, stream,
                       u, ws, out);
}